// Round 14
// baseline (84.624 us; speedup 1.0000x reference)
//
#include <hip/hip_runtime.h>
#include <hip/hip_bf16.h>
#include <math.h>

#define Bn 4096
#define Hn 200

typedef float f32x16 __attribute__((ext_vector_type(16)));
typedef short short8 __attribute__((ext_vector_type(8)));
typedef __bf16 bh8 __attribute__((ext_vector_type(8)));
typedef unsigned int u32;

// ---- d_ws layout (u32 units) ----
#define TABW     3200000
#define BIAS_OFF 10240
#define WR_OFF   10496
#define AT3_OFF  10560
#define WTOT     10624

__device__ __forceinline__ u32 pk2(float a, float b){
    union { __hip_bfloat162 bf; u32 u; } cv;
    cv.bf = __float22bfloat162_rn(make_float2(a, b));   // low 16 bits = first k
    return cv.u;
}

template <typename T>
__device__ __forceinline__ auto mfma_sel(T a, T b, f32x16 c, int)
    -> decltype(__builtin_amdgcn_mfma_f32_32x32x16_bf16(a, b, c, 0, 0, 0)) {
    return __builtin_amdgcn_mfma_f32_32x32x16_bf16(a, b, c, 0, 0, 0);
}
template <typename T>
__device__ __forceinline__ f32x16 mfma_sel(T a, T b, f32x16 c, long) {
    return __builtin_amdgcn_mfma_f32_32x32x16_bf16(
        __builtin_bit_cast(bh8, a), __builtin_bit_cast(bh8, b), c, 0, 0, 0);
}
__device__ __forceinline__ f32x16 mfma_u4(uint4 a, uint4 b, f32x16 c){
    return mfma_sel(__builtin_bit_cast(short8, a), __builtin_bit_cast(short8, b), c, 0);
}

// packed ReLU (v_pk_max_f32 when available)
__device__ __forceinline__ f32x16 relu16(f32x16 a){
#if __has_builtin(__builtin_elementwise_max)
    return __builtin_elementwise_max(a, (f32x16)(0.f));
#else
#pragma unroll
    for (int i = 0; i < 16; ++i) a[i] = fmaxf(a[i], 0.f);
    return a;
#endif
}

// D-tile (col=lane&31, row=(reg&3)+8*(reg>>2)+4*(lane>>5)) -> next-layer B frags
__device__ __forceinline__ void dtile_to_b(f32x16 d, uint4& b0, uint4& b1){
    u32 p0 = pk2(d[0], d[1]),   p1 = pk2(d[2], d[3]);
    u32 p2 = pk2(d[4], d[5]),   p3 = pk2(d[6], d[7]);
    u32 p4 = pk2(d[8], d[9]),   p5 = pk2(d[10], d[11]);
    u32 p6 = pk2(d[12], d[13]), p7 = pk2(d[14], d[15]);
    auto r0 = __builtin_amdgcn_permlane32_swap(p0, p2, false, false);
    auto r1 = __builtin_amdgcn_permlane32_swap(p1, p3, false, false);
    auto r2 = __builtin_amdgcn_permlane32_swap(p4, p6, false, false);
    auto r3 = __builtin_amdgcn_permlane32_swap(p5, p7, false, false);
    b0 = make_uint4((u32)r0[0], (u32)r1[0], (u32)r0[1], (u32)r1[1]);
    b1 = make_uint4((u32)r2[0], (u32)r3[0], (u32)r2[1], (u32)r3[1]);
}

// ======================= prep: pack weights (+ bf16 table) =======================
__global__ __launch_bounds__(256) void prep(
    const float* __restrict__ v2e_w,
    const float* __restrict__ w_r1_w, const float* __restrict__ w_r1_b,
    const float* __restrict__ w_r2_w, const float* __restrict__ w_r2_b,
    const float* __restrict__ att1_w, const float* __restrict__ att1_b,
    const float* __restrict__ att2_w, const float* __restrict__ att2_b,
    const float* __restrict__ att3_w,
    u32* __restrict__ ws, int table_n, int woff)
{
    const int g = blockIdx.x * 256 + threadIdx.x;
    if (g < table_n) {
        const float4* src = (const float4*)v2e_w + (size_t)g * 2;
        float4 a = src[0], b = src[1];
        uint4 o; o.x = pk2(a.x, a.y); o.y = pk2(a.z, a.w);
                 o.z = pk2(b.x, b.y); o.w = pk2(b.z, b.w);
        ((uint4*)ws)[g] = o;
        return;
    }
    int q = g - table_n;
    u32* wbase = ws + woff;
    if (q < 2560) {
        const int c = q >> 6, l = q & 63, lo = l & 31, h = l >> 5;
        const float* W; int ldw, ft, kc, colb;
        if (c < 8)       { W = w_r1_w; ldw = 65;  ft = c >> 2;       kc = c & 3;       colb = 0; }
        else if (c < 16) { W = w_r2_w; ldw = 64;  ft = (c - 8) >> 2; kc = (c - 8) & 3; colb = 0; }
        else if (c < 32) { int c3 = c - 16; W = att1_w; ldw = 128; ft = c3 >> 3; kc = c3 & 3; colb = 64 * ((c3 >> 2) & 1); }
        else             { int c4 = c - 32; W = att2_w; ldw = 64;  ft = c4 >> 2; kc = c4 & 3; colb = 0; }
        const float* p = W + (32 * ft + lo) * ldw + colb + 16 * kc + 8 * h;
        uint4 o; o.x = pk2(p[0], p[1]); o.y = pk2(p[2], p[3]);
                 o.z = pk2(p[4], p[5]); o.w = pk2(p[6], p[7]);
        ((uint4*)wbase)[c * 64 + l] = o;
        return;
    }
    q -= 2560;
    if (q < 256) {
        const int layer = q >> 6, ft = (q >> 5) & 1, h = (q >> 4) & 1, rg = q & 15;
        const float* bp = layer == 0 ? w_r1_b : layer == 1 ? w_r2_b : layer == 2 ? att1_b : att2_b;
        ((float*)wbase)[BIAS_OFF + q] = bp[32 * ft + (rg & 3) + 8 * (rg >> 2) + 4 * h];
        return;
    }
    q -= 256;
    if (q < 64) {
        const int ft = (q >> 5) & 1, h = (q >> 4) & 1, rg = q & 15;
        ((float*)wbase)[WR_OFF + q] = w_r1_w[(32 * ft + (rg & 3) + 8 * (rg >> 2) + 4 * h) * 65 + 64];
        return;
    }
    q -= 64;
    if (q < 64) {
        const int ft = (q >> 5) & 1, h = (q >> 4) & 1, rg = q & 15;
        ((float*)wbase)[AT3_OFF + q] = att3_w[32 * ft + (rg & 3) + 8 * (rg >> 2) + 4 * h];
    }
}

// ======================= main: 4 waves x 2 tiles of 32 rows, 4 blocks/CU =======================
template<int USE_TAB>
__global__ __launch_bounds__(256, 4) void uv_agg(
    const int* __restrict__ nodes,
    const int* __restrict__ history_uv,
    const float* __restrict__ history_r,
    const float* __restrict__ u2e_w,
    const float* __restrict__ v2e_w,
    const float* __restrict__ att3_b,
    const u32* __restrict__ ws,
    float* __restrict__ out)
{
    const int b  = blockIdx.x;
    const int t  = threadIdx.x;
    const int w  = t >> 6;
    const int l  = t & 63;
    const int lo = l & 31;
    const int h  = l >> 5;

    constexpr int woff = USE_TAB ? TABW : 0;
    const uint4* WF = (const uint4*)(ws + woff);
    const float* F  = (const float*)(ws + woff);

    // word col c of row m stored at q = c ^ ((m&15)<<1)  (pair-preserving -> b64 ops)
    __shared__ u32   oh_lds[224 * 32];   // 28 KB (rows 200-223 hold clamped duplicates; att=0 masks them)
    __shared__ float att_lds[256];
    __shared__ float red[4][64];
    __shared__ float ssum[4];
    __shared__ u32   u_lds[32];

    if (t < 32) {
        const float2 uv = ((const float2*)(u2e_w + (size_t)nodes[b] * 64))[t];
        u_lds[t] = pk2(uv.x, uv.y);
    }

    const bool full = (w != 3);          // wave 3's tile 2 (rows 224-255) is all pad

    const int hb  = b * Hn;
    const int m0  = 64 * w + lo;
    const int m1  = m0 + 32;
    const int mi0 = m0 < Hn ? m0 : Hn - 1;
    const int mi1 = m1 < Hn ? m1 : Hn - 1;
    const int vidx0 = history_uv[hb + mi0];
    float rv[2];
    rv[0] = history_r[hb + mi0];
    rv[1] = history_r[hb + mi1];

    // ---- e_uv B-fragments (tile 2 only for full waves)
    uint4 eB[2][4];
    if constexpr (USE_TAB) {
        const uint4* t0 = (const uint4*)ws + (size_t)vidx0 * 8;
#pragma unroll
        for (int kc = 0; kc < 4; ++kc) eB[0][kc] = t0[2*kc + h];
        if (full) {
            const uint4* t1 = (const uint4*)ws + (size_t)history_uv[hb + mi1] * 8;
#pragma unroll
            for (int kc = 0; kc < 4; ++kc) eB[1][kc] = t1[2*kc + h];
        }
    } else {
        const float4* p0 = (const float4*)(v2e_w + (size_t)vidx0 * 64);
#pragma unroll
        for (int kc = 0; kc < 4; ++kc){
            float4 a = p0[4*kc + 2*h], c = p0[4*kc + 2*h + 1];
            eB[0][kc] = make_uint4(pk2(a.x, a.y), pk2(a.z, a.w), pk2(c.x, c.y), pk2(c.z, c.w));
        }
        if (full) {
            const float4* p1 = (const float4*)(v2e_w + (size_t)history_uv[hb + mi1] * 64);
#pragma unroll
            for (int kc = 0; kc < 4; ++kc){
                float4 a = p1[4*kc + 2*h], c = p1[4*kc + 2*h + 1];
                eB[1][kc] = make_uint4(pk2(a.x, a.y), pk2(a.z, a.w), pk2(c.x, c.y), pk2(c.z, c.w));
            }
        }
    }

    // ---- layer 1: x1 = relu(W1[:,:64] @ e + w1r*r + b1)
    uint4 x1B[2][4];
#pragma unroll
    for (int ft = 0; ft < 2; ++ft){
        uint4 W[4];
#pragma unroll
        for (int kc = 0; kc < 4; ++kc) W[kc] = WF[(ft*4 + kc)*64 + l];
        const f32x16 bv = *(const f32x16*)(F + BIAS_OFF + ft*32 + h*16);
        const f32x16 wv = *(const f32x16*)(F + WR_OFF  + ft*32 + h*16);
#pragma unroll
        for (int rt = 0; rt < 2; ++rt){
            if (rt == 0 || full) {
                f32x16 a = wv * rv[rt] + bv;       // packed fma
#pragma unroll
                for (int kc = 0; kc < 4; ++kc) a = mfma_u4(W[kc], eB[rt][kc], a);
                a = relu16(a);
                dtile_to_b(a, x1B[rt][2*ft], x1B[rt][2*ft+1]);
            }
        }
    }

    // ---- layer 2: o_history = relu(W2 @ x1 + b2) -> kept in regs; also stashed to LDS for finale
    uint4 ohB[2][4];
#pragma unroll
    for (int ft = 0; ft < 2; ++ft){
        uint4 W[4];
#pragma unroll
        for (int kc = 0; kc < 4; ++kc) W[kc] = WF[(8 + ft*4 + kc)*64 + l];
        const f32x16 bv = *(const f32x16*)(F + BIAS_OFF + 64 + ft*32 + h*16);
#pragma unroll
        for (int rt = 0; rt < 2; ++rt){
            if (rt == 0 || full) {
                f32x16 a = bv;
#pragma unroll
                for (int kc = 0; kc < 4; ++kc) a = mfma_u4(W[kc], x1B[rt][kc], a);
                a = relu16(a);
                uint4 b0, b1;
                dtile_to_b(a, b0, b1);
                ohB[rt][2*ft]   = b0;
                ohB[rt][2*ft+1] = b1;
                const int m = 64 * w + 32 * rt + lo;   // < 224 always (wave3 rt1 skipped)
                uint2* oh2 = (uint2*)oh_lds;
                const int x  = (lo & 15) << 1;
                const int q0 = (16*ft + 4*h) ^ x;      // c0 = 8*(2ft)+4h
                const int base = m * 16;
                oh2[base + ( q0      >> 1)] = make_uint2(b0.x, b0.y);
                oh2[base + ((q0 ^ 2) >> 1)] = make_uint2(b0.z, b0.w);
                oh2[base + ((q0 ^ 8) >> 1)] = make_uint2(b1.x, b1.y);
                oh2[base + ((q0 ^10) >> 1)] = make_uint2(b1.z, b1.w);
            }
        }
    }

    __syncthreads();   // u_lds ready

    // ---- layer 3: a1 = relu(A1 @ [oh ; u] + b)  K=128; u-part once per ft; oh from REGISTERS
    uint4 a1B[2][4];
#pragma unroll
    for (int ft = 0; ft < 2; ++ft){
        f32x16 accu = *(const f32x16*)(F + BIAS_OFF + 128 + ft*32 + h*16);
        {
            uint4 Wu[4];
#pragma unroll
            for (int kc = 0; kc < 4; ++kc) Wu[kc] = WF[(16 + ft*8 + 4 + kc)*64 + l];
#pragma unroll
            for (int kc = 0; kc < 4; ++kc){
                uint4 uu = *(const uint4*)&u_lds[8*kc + 4*h];
                accu = mfma_u4(Wu[kc], uu, accu);
            }
        }
        uint4 Wo[4];
#pragma unroll
        for (int kc = 0; kc < 4; ++kc) Wo[kc] = WF[(16 + ft*8 + kc)*64 + l];
#pragma unroll
        for (int rt = 0; rt < 2; ++rt){
            if (rt == 0 || full) {
                f32x16 a = accu;
#pragma unroll
                for (int kc = 0; kc < 4; ++kc) a = mfma_u4(Wo[kc], ohB[rt][kc], a);
                a = relu16(a);
                dtile_to_b(a, a1B[rt][2*ft], a1B[rt][2*ft+1]);
            }
        }
    }

    // ---- layer 4 + logit dot
    float lgp[2] = {0.f, 0.f};
#pragma unroll
    for (int ft = 0; ft < 2; ++ft){
        uint4 W[4];
#pragma unroll
        for (int kc = 0; kc < 4; ++kc) W[kc] = WF[(32 + ft*4 + kc)*64 + l];
        const f32x16 bv = *(const f32x16*)(F + BIAS_OFF + 192 + ft*32 + h*16);
        const f32x16 a3 = *(const f32x16*)(F + AT3_OFF + ft*32 + h*16);
#pragma unroll
        for (int rt = 0; rt < 2; ++rt){
            if (rt == 0 || full) {
                f32x16 a = bv;
#pragma unroll
                for (int kc = 0; kc < 4; ++kc) a = mfma_u4(W[kc], a1B[rt][kc], a);
                f32x16 p = relu16(a) * a3;
                float d0 = (p[0] + p[1]) + (p[2] + p[3]);
                float d1 = (p[4] + p[5]) + (p[6] + p[7]);
                float d2 = (p[8] + p[9]) + (p[10] + p[11]);
                float d3 = (p[12] + p[13]) + (p[14] + p[15]);
                lgp[rt] += (d0 + d1) + (d2 + d3);
            }
        }
    }
    const float b3 = att3_b[0];
    float lg0 = lgp[0] + __shfl_xor(lgp[0], 32, 64) + b3;
    float lg1 = lgp[1] + __shfl_xor(lgp[1], 32, 64) + b3;
    if (m0 >= Hn) lg0 = -1e30f;
    if (m1 >= Hn || !full) lg1 = -1e30f;

    // ---- softmax over 200 rows (no max pass: logits bounded, shift-invariant ratio)
    const float e0 = exp2f(lg0 * 1.4426950408889634f);
    const float e1 = exp2f(lg1 * 1.4426950408889634f);
    float sm = e0 + e1;
#pragma unroll
    for (int d = 16; d >= 1; d >>= 1) sm += __shfl_xor(sm, d, 64);
    if (l == 0) ssum[w] = sm;
    __syncthreads();
    const float inv = 1.f / (ssum[0] + ssum[1] + ssum[2] + ssum[3]);
    att_lds[64 * w + 32 * h + lo] = (h ? e1 : e0) * inv;
    __syncthreads();

    // ---- weighted sum over this wave's 64 rows (h-split)
    float s0 = 0.f, s1 = 0.f;
#pragma unroll 8
    for (int i = 0; i < 32; ++i){
        const int row = 64 * w + 32 * h + i;
        const int ri  = row < 224 ? row : Hn - 1;     // only wave3/h1 tail clamps
        const u32 wv  = oh_lds[ri * 32 + (lo ^ ((ri & 15) << 1))];
        const float av = att_lds[row];                // 0 for pad rows
        s0 = fmaf(__uint_as_float(wv << 16), av, s0);
        s1 = fmaf(__uint_as_float(wv & 0xffff0000u), av, s1);
    }
    s0 += __shfl_xor(s0, 32, 64);
    s1 += __shfl_xor(s1, 32, 64);
    if (l < 32){ red[w][2 * lo] = s0; red[w][2 * lo + 1] = s1; }
    __syncthreads();
    if (t < 64)
        out[b * 64 + t] = red[0][t] + red[1][t] + red[2][t] + red[3][t];
}

extern "C" void kernel_launch(void* const* d_in, const int* in_sizes, int n_in,
                              void* d_out, int out_size, void* d_ws, size_t ws_size,
                              hipStream_t stream) {
    u32* ws = (u32*)d_ws;
    const size_t need_tab = (size_t)(TABW + WTOT) * 4;
    const int use_tab = (ws_size >= need_tab) ? 1 : 0;
    const int woff    = use_tab ? TABW : 0;
    const int table_n = use_tab ? 800000 : 0;
    const int prep_threads = table_n + 2944;
    const int prep_blocks  = (prep_threads + 255) / 256;

    prep<<<prep_blocks, 256, 0, stream>>>(
        (const float*)d_in[4],
        (const float*)d_in[5],  (const float*)d_in[6],
        (const float*)d_in[7],  (const float*)d_in[8],
        (const float*)d_in[9],  (const float*)d_in[10],
        (const float*)d_in[11], (const float*)d_in[12],
        (const float*)d_in[13],
        ws, table_n, woff);

    if (use_tab) {
        uv_agg<1><<<Bn, 256, 0, stream>>>(
            (const int*)d_in[0], (const int*)d_in[1], (const float*)d_in[2],
            (const float*)d_in[3], (const float*)d_in[4], (const float*)d_in[14],
            ws, (float*)d_out);
    } else {
        uv_agg<0><<<Bn, 256, 0, stream>>>(
            (const int*)d_in[0], (const int*)d_in[1], (const float*)d_in[2],
            (const float*)d_in[3], (const float*)d_in[4], (const float*)d_in[14],
            ws, (float*)d_out);
    }
}

// Round 15
// 81.178 us; speedup vs baseline: 1.0425x; 1.0425x over previous
//
#include <hip/hip_runtime.h>
#include <hip/hip_bf16.h>
#include <math.h>

#define Bn 4096
#define Hn 200

typedef float f32x16 __attribute__((ext_vector_type(16)));
typedef short short8 __attribute__((ext_vector_type(8)));
typedef __bf16 bh8 __attribute__((ext_vector_type(8)));
typedef unsigned int u32;

// ---- d_ws layout (u32 units) ----
#define TABW     3200000
#define BIAS_OFF 10240
#define WR_OFF   10496
#define AT3_OFF  10560
#define WTOT     10624

__device__ __forceinline__ u32 pk2(float a, float b){
    union { __hip_bfloat162 bf; u32 u; } cv;
    cv.bf = __float22bfloat162_rn(make_float2(a, b));   // low 16 bits = first k
    return cv.u;
}

template <typename T>
__device__ __forceinline__ auto mfma_sel(T a, T b, f32x16 c, int)
    -> decltype(__builtin_amdgcn_mfma_f32_32x32x16_bf16(a, b, c, 0, 0, 0)) {
    return __builtin_amdgcn_mfma_f32_32x32x16_bf16(a, b, c, 0, 0, 0);
}
template <typename T>
__device__ __forceinline__ f32x16 mfma_sel(T a, T b, f32x16 c, long) {
    return __builtin_amdgcn_mfma_f32_32x32x16_bf16(
        __builtin_bit_cast(bh8, a), __builtin_bit_cast(bh8, b), c, 0, 0, 0);
}
__device__ __forceinline__ f32x16 mfma_u4(uint4 a, uint4 b, f32x16 c){
    return mfma_sel(__builtin_bit_cast(short8, a), __builtin_bit_cast(short8, b), c, 0);
}

// packed ReLU (v_pk_max_f32 when available)
__device__ __forceinline__ f32x16 relu16(f32x16 a){
#if __has_builtin(__builtin_elementwise_max)
    return __builtin_elementwise_max(a, (f32x16)(0.f));
#else
#pragma unroll
    for (int i = 0; i < 16; ++i) a[i] = fmaxf(a[i], 0.f);
    return a;
#endif
}

// D-tile (col=lane&31, row=(reg&3)+8*(reg>>2)+4*(lane>>5)) -> next-layer B frags
__device__ __forceinline__ void dtile_to_b(f32x16 d, uint4& b0, uint4& b1){
    u32 p0 = pk2(d[0], d[1]),   p1 = pk2(d[2], d[3]);
    u32 p2 = pk2(d[4], d[5]),   p3 = pk2(d[6], d[7]);
    u32 p4 = pk2(d[8], d[9]),   p5 = pk2(d[10], d[11]);
    u32 p6 = pk2(d[12], d[13]), p7 = pk2(d[14], d[15]);
    auto r0 = __builtin_amdgcn_permlane32_swap(p0, p2, false, false);
    auto r1 = __builtin_amdgcn_permlane32_swap(p1, p3, false, false);
    auto r2 = __builtin_amdgcn_permlane32_swap(p4, p6, false, false);
    auto r3 = __builtin_amdgcn_permlane32_swap(p5, p7, false, false);
    b0 = make_uint4((u32)r0[0], (u32)r1[0], (u32)r0[1], (u32)r1[1]);
    b1 = make_uint4((u32)r2[0], (u32)r3[0], (u32)r2[1], (u32)r3[1]);
}

// ======================= prep: pack weights (+ bf16 table) =======================
__global__ __launch_bounds__(256) void prep(
    const float* __restrict__ v2e_w,
    const float* __restrict__ w_r1_w, const float* __restrict__ w_r1_b,
    const float* __restrict__ w_r2_w, const float* __restrict__ w_r2_b,
    const float* __restrict__ att1_w, const float* __restrict__ att1_b,
    const float* __restrict__ att2_w, const float* __restrict__ att2_b,
    const float* __restrict__ att3_w,
    u32* __restrict__ ws, int table_n, int woff)
{
    const int g = blockIdx.x * 256 + threadIdx.x;
    if (g < table_n) {
        const float4* src = (const float4*)v2e_w + (size_t)g * 2;
        float4 a = src[0], b = src[1];
        uint4 o; o.x = pk2(a.x, a.y); o.y = pk2(a.z, a.w);
                 o.z = pk2(b.x, b.y); o.w = pk2(b.z, b.w);
        ((uint4*)ws)[g] = o;
        return;
    }
    int q = g - table_n;
    u32* wbase = ws + woff;
    if (q < 2560) {
        const int c = q >> 6, l = q & 63, lo = l & 31, h = l >> 5;
        const float* W; int ldw, ft, kc, colb;
        if (c < 8)       { W = w_r1_w; ldw = 65;  ft = c >> 2;       kc = c & 3;       colb = 0; }
        else if (c < 16) { W = w_r2_w; ldw = 64;  ft = (c - 8) >> 2; kc = (c - 8) & 3; colb = 0; }
        else if (c < 32) { int c3 = c - 16; W = att1_w; ldw = 128; ft = c3 >> 3; kc = c3 & 3; colb = 64 * ((c3 >> 2) & 1); }
        else             { int c4 = c - 32; W = att2_w; ldw = 64;  ft = c4 >> 2; kc = c4 & 3; colb = 0; }
        const float* p = W + (32 * ft + lo) * ldw + colb + 16 * kc + 8 * h;
        uint4 o; o.x = pk2(p[0], p[1]); o.y = pk2(p[2], p[3]);
                 o.z = pk2(p[4], p[5]); o.w = pk2(p[6], p[7]);
        ((uint4*)wbase)[c * 64 + l] = o;
        return;
    }
    q -= 2560;
    if (q < 256) {
        const int layer = q >> 6, ft = (q >> 5) & 1, h = (q >> 4) & 1, rg = q & 15;
        const float* bp = layer == 0 ? w_r1_b : layer == 1 ? w_r2_b : layer == 2 ? att1_b : att2_b;
        ((float*)wbase)[BIAS_OFF + q] = bp[32 * ft + (rg & 3) + 8 * (rg >> 2) + 4 * h];
        return;
    }
    q -= 256;
    if (q < 64) {
        const int ft = (q >> 5) & 1, h = (q >> 4) & 1, rg = q & 15;
        ((float*)wbase)[WR_OFF + q] = w_r1_w[(32 * ft + (rg & 3) + 8 * (rg >> 2) + 4 * h) * 65 + 64];
        return;
    }
    q -= 64;
    if (q < 64) {
        const int ft = (q >> 5) & 1, h = (q >> 4) & 1, rg = q & 15;
        ((float*)wbase)[AT3_OFF + q] = att3_w[32 * ft + (rg & 3) + 8 * (rg >> 2) + 4 * h];
    }
}

// ======================= main: 4 waves x 2 tiles of 32 rows, 4 blocks/CU =======================
template<int USE_TAB>
__global__ __launch_bounds__(256, 4) void uv_agg(
    const int* __restrict__ nodes,
    const int* __restrict__ history_uv,
    const float* __restrict__ history_r,
    const float* __restrict__ u2e_w,
    const float* __restrict__ v2e_w,
    const float* __restrict__ att3_b,
    const u32* __restrict__ ws,
    float* __restrict__ out)
{
    const int b  = blockIdx.x;
    const int t  = threadIdx.x;
    const int w  = t >> 6;
    const int l  = t & 63;
    const int lo = l & 31;
    const int h  = l >> 5;

    constexpr int woff = USE_TAB ? TABW : 0;
    const uint4* WF = (const uint4*)(ws + woff);
    const float* F  = (const float*)(ws + woff);

    // word col c of row m stored at q = c ^ ((m&15)<<1)  (pair-preserving -> b64 ops)
    __shared__ u32   oh_lds[224 * 32];   // 28 KB (rows 200-223 hold clamped duplicates; att=0 masks them)
    __shared__ float red[4][64];
    __shared__ float ssum[4];
    __shared__ u32   u_lds[32];

    if (t < 32) {
        const float2 uv = ((const float2*)(u2e_w + (size_t)nodes[b] * 64))[t];
        u_lds[t] = pk2(uv.x, uv.y);
    }

    const bool full = (w != 3);          // wave 3's tile 2 (rows 224-255) is all pad

    const int hb  = b * Hn;
    const int m0  = 64 * w + lo;
    const int m1  = m0 + 32;
    const int mi0 = m0 < Hn ? m0 : Hn - 1;
    const int mi1 = m1 < Hn ? m1 : Hn - 1;
    const int vidx0 = history_uv[hb + mi0];
    float rv[2];
    rv[0] = history_r[hb + mi0];
    rv[1] = history_r[hb + mi1];

    // ---- e_uv B-fragments (tile 2 only for full waves)
    uint4 eB[2][4];
    if constexpr (USE_TAB) {
        const uint4* t0 = (const uint4*)ws + (size_t)vidx0 * 8;
#pragma unroll
        for (int kc = 0; kc < 4; ++kc) eB[0][kc] = t0[2*kc + h];
        if (full) {
            const uint4* t1 = (const uint4*)ws + (size_t)history_uv[hb + mi1] * 8;
#pragma unroll
            for (int kc = 0; kc < 4; ++kc) eB[1][kc] = t1[2*kc + h];
        }
    } else {
        const float4* p0 = (const float4*)(v2e_w + (size_t)vidx0 * 64);
#pragma unroll
        for (int kc = 0; kc < 4; ++kc){
            float4 a = p0[4*kc + 2*h], c = p0[4*kc + 2*h + 1];
            eB[0][kc] = make_uint4(pk2(a.x, a.y), pk2(a.z, a.w), pk2(c.x, c.y), pk2(c.z, c.w));
        }
        if (full) {
            const float4* p1 = (const float4*)(v2e_w + (size_t)history_uv[hb + mi1] * 64);
#pragma unroll
            for (int kc = 0; kc < 4; ++kc){
                float4 a = p1[4*kc + 2*h], c = p1[4*kc + 2*h + 1];
                eB[1][kc] = make_uint4(pk2(a.x, a.y), pk2(a.z, a.w), pk2(c.x, c.y), pk2(c.z, c.w));
            }
        }
    }

    // ---- layer 1: x1 = relu(W1[:,:64] @ e + w1r*r + b1)
    uint4 x1B[2][4];
#pragma unroll
    for (int ft = 0; ft < 2; ++ft){
        uint4 W[4];
#pragma unroll
        for (int kc = 0; kc < 4; ++kc) W[kc] = WF[(ft*4 + kc)*64 + l];
        const f32x16 bv = *(const f32x16*)(F + BIAS_OFF + ft*32 + h*16);
        const f32x16 wv = *(const f32x16*)(F + WR_OFF  + ft*32 + h*16);
#pragma unroll
        for (int rt = 0; rt < 2; ++rt){
            if (rt == 0 || full) {
                f32x16 a = wv * rv[rt] + bv;       // packed fma
                __builtin_amdgcn_s_setprio(1);
#pragma unroll
                for (int kc = 0; kc < 4; ++kc) a = mfma_u4(W[kc], eB[rt][kc], a);
                __builtin_amdgcn_s_setprio(0);
                a = relu16(a);
                dtile_to_b(a, x1B[rt][2*ft], x1B[rt][2*ft+1]);
            }
        }
    }

    // ---- layer 2: o_history = relu(W2 @ x1 + b2)  -> straight into LDS
#pragma unroll
    for (int ft = 0; ft < 2; ++ft){
        uint4 W[4];
#pragma unroll
        for (int kc = 0; kc < 4; ++kc) W[kc] = WF[(8 + ft*4 + kc)*64 + l];
        const f32x16 bv = *(const f32x16*)(F + BIAS_OFF + 64 + ft*32 + h*16);
#pragma unroll
        for (int rt = 0; rt < 2; ++rt){
            if (rt == 0 || full) {
                f32x16 a = bv;
                __builtin_amdgcn_s_setprio(1);
#pragma unroll
                for (int kc = 0; kc < 4; ++kc) a = mfma_u4(W[kc], x1B[rt][kc], a);
                __builtin_amdgcn_s_setprio(0);
                a = relu16(a);
                uint4 b0, b1;
                dtile_to_b(a, b0, b1);
                const int m = 64 * w + 32 * rt + lo;   // < 224 always (wave3 rt1 skipped)
                uint2* oh2 = (uint2*)oh_lds;
                const int x  = (lo & 15) << 1;
                const int q0 = (16*ft + 4*h) ^ x;      // c0 = 8*(2ft)+4h
                const int base = m * 16;
                oh2[base + ( q0      >> 1)] = make_uint2(b0.x, b0.y);
                oh2[base + ((q0 ^ 2) >> 1)] = make_uint2(b0.z, b0.w);
                oh2[base + ((q0 ^ 8) >> 1)] = make_uint2(b1.x, b1.y);
                oh2[base + ((q0 ^10) >> 1)] = make_uint2(b1.z, b1.w);
            }
        }
    }

    __syncthreads();   // u_lds ready; oh stash ordered

    // ---- layer 3: a1 = relu(A1 @ [oh ; u] + b)  K=128; u-part computed once per ft
    uint4 a1B[2][4];
#pragma unroll
    for (int ft = 0; ft < 2; ++ft){
        f32x16 accu = *(const f32x16*)(F + BIAS_OFF + 128 + ft*32 + h*16);
        {
            uint4 Wu[4];
#pragma unroll
            for (int kc = 0; kc < 4; ++kc) Wu[kc] = WF[(16 + ft*8 + 4 + kc)*64 + l];
            __builtin_amdgcn_s_setprio(1);
#pragma unroll
            for (int kc = 0; kc < 4; ++kc){
                uint4 uu = *(const uint4*)&u_lds[8*kc + 4*h];
                accu = mfma_u4(Wu[kc], uu, accu);
            }
            __builtin_amdgcn_s_setprio(0);
        }
        uint4 Wo[4];
#pragma unroll
        for (int kc = 0; kc < 4; ++kc) Wo[kc] = WF[(16 + ft*8 + kc)*64 + l];
#pragma unroll
        for (int rt = 0; rt < 2; ++rt){
            if (rt == 0 || full) {
                const int m = 64 * w + 32 * rt + lo;
                const int x = (lo & 15) << 1;
                const uint2* oh2 = (const uint2*)oh_lds;
                uint4 frag[4];
#pragma unroll
                for (int kc = 0; kc < 4; ++kc){
                    const int q = (8*kc + 4*h) ^ x;
                    uint2 ra = oh2[m*16 + ( q      >> 1)];
                    uint2 rb = oh2[m*16 + ((q ^ 2) >> 1)];
                    frag[kc] = make_uint4(ra.x, ra.y, rb.x, rb.y);
                }
                f32x16 a = accu;
                __builtin_amdgcn_s_setprio(1);
#pragma unroll
                for (int kc = 0; kc < 4; ++kc) a = mfma_u4(Wo[kc], frag[kc], a);
                __builtin_amdgcn_s_setprio(0);
                a = relu16(a);
                dtile_to_b(a, a1B[rt][2*ft], a1B[rt][2*ft+1]);
            }
        }
    }

    // ---- layer 4 + logit dot
    float lgp[2] = {0.f, 0.f};
#pragma unroll
    for (int ft = 0; ft < 2; ++ft){
        uint4 W[4];
#pragma unroll
        for (int kc = 0; kc < 4; ++kc) W[kc] = WF[(32 + ft*4 + kc)*64 + l];
        const f32x16 bv = *(const f32x16*)(F + BIAS_OFF + 192 + ft*32 + h*16);
        const f32x16 a3 = *(const f32x16*)(F + AT3_OFF + ft*32 + h*16);
#pragma unroll
        for (int rt = 0; rt < 2; ++rt){
            if (rt == 0 || full) {
                f32x16 a = bv;
                __builtin_amdgcn_s_setprio(1);
#pragma unroll
                for (int kc = 0; kc < 4; ++kc) a = mfma_u4(W[kc], a1B[rt][kc], a);
                __builtin_amdgcn_s_setprio(0);
                f32x16 p = relu16(a) * a3;
                float d0 = (p[0] + p[1]) + (p[2] + p[3]);
                float d1 = (p[4] + p[5]) + (p[6] + p[7]);
                float d2 = (p[8] + p[9]) + (p[10] + p[11]);
                float d3 = (p[12] + p[13]) + (p[14] + p[15]);
                lgp[rt] += (d0 + d1) + (d2 + d3);
            }
        }
    }
    const float b3 = att3_b[0];
    float lg0 = lgp[0] + __shfl_xor(lgp[0], 32, 64) + b3;
    float lg1 = lgp[1] + __shfl_xor(lgp[1], 32, 64) + b3;
    if (m0 >= Hn) lg0 = -1e30f;
    if (m1 >= Hn || !full) lg1 = -1e30f;

    // ---- softmax over 200 rows (no max pass: logits bounded, shift-invariant ratio)
    const float e0 = exp2f(lg0 * 1.4426950408889634f);
    const float e1 = exp2f(lg1 * 1.4426950408889634f);
    float sm = e0 + e1;
#pragma unroll
    for (int d = 16; d >= 1; d >>= 1) sm += __shfl_xor(sm, d, 64);
    if (l == 0) ssum[w] = sm;
    __syncthreads();
    const float inv = 1.f / (ssum[0] + ssum[1] + ssum[2] + ssum[3]);
    // lane (lo,h) holds att numerator for row 64w+32h+lo (uniform across half-pairs)
    const float avv = (h ? e1 : e0) * inv;

    // ---- weighted sum over this wave's 64 rows (h-split; att via shfl, no LDS/barrier)
    float s0 = 0.f, s1 = 0.f;
#pragma unroll 8
    for (int i = 0; i < 32; ++i){
        const int row = 64 * w + 32 * h + i;
        const int ri  = row < 224 ? row : Hn - 1;     // only wave3/h1 tail clamps
        const u32 wv  = oh_lds[ri * 32 + (lo ^ ((ri & 15) << 1))];
        const float av = __shfl(avv, 32 * h + i, 64); // 0 for pad rows
        s0 = fmaf(__uint_as_float(wv << 16), av, s0);
        s1 = fmaf(__uint_as_float(wv & 0xffff0000u), av, s1);
    }
    s0 += __shfl_xor(s0, 32, 64);
    s1 += __shfl_xor(s1, 32, 64);
    if (l < 32){ red[w][2 * lo] = s0; red[w][2 * lo + 1] = s1; }
    __syncthreads();
    if (t < 64)
        out[b * 64 + t] = red[0][t] + red[1][t] + red[2][t] + red[3][t];
}

extern "C" void kernel_launch(void* const* d_in, const int* in_sizes, int n_in,
                              void* d_out, int out_size, void* d_ws, size_t ws_size,
                              hipStream_t stream) {
    u32* ws = (u32*)d_ws;
    const size_t need_tab = (size_t)(TABW + WTOT) * 4;
    const int use_tab = (ws_size >= need_tab) ? 1 : 0;
    const int woff    = use_tab ? TABW : 0;
    const int table_n = use_tab ? 800000 : 0;
    const int prep_threads = table_n + 2944;
    const int prep_blocks  = (prep_threads + 255) / 256;

    prep<<<prep_blocks, 256, 0, stream>>>(
        (const float*)d_in[4],
        (const float*)d_in[5],  (const float*)d_in[6],
        (const float*)d_in[7],  (const float*)d_in[8],
        (const float*)d_in[9],  (const float*)d_in[10],
        (const float*)d_in[11], (const float*)d_in[12],
        (const float*)d_in[13],
        ws, table_n, woff);

    if (use_tab) {
        uv_agg<1><<<Bn, 256, 0, stream>>>(
            (const int*)d_in[0], (const int*)d_in[1], (const float*)d_in[2],
            (const float*)d_in[3], (const float*)d_in[4], (const float*)d_in[14],
            ws, (float*)d_out);
    } else {
        uv_agg<0><<<Bn, 256, 0, stream>>>(
            (const int*)d_in[0], (const int*)d_in[1], (const float*)d_in[2],
            (const float*)d_in[3], (const float*)d_in[4], (const float*)d_in[14],
            ws, (float*)d_out);
    }
}

// Round 16
// 80.438 us; speedup vs baseline: 1.0520x; 1.0092x over previous
//
#include <hip/hip_runtime.h>
#include <hip/hip_bf16.h>
#include <math.h>

#define Bn 4096
#define Hn 200

typedef float f32x16 __attribute__((ext_vector_type(16)));
typedef short short8 __attribute__((ext_vector_type(8)));
typedef __bf16 bh8 __attribute__((ext_vector_type(8)));
typedef unsigned int u32;

// ---- d_ws layout (u32 units) ----
#define TABW     3200000
#define BIAS_OFF 10240
#define WR_OFF   10496
#define AT3_OFF  10560
#define WTOT     10624

__device__ __forceinline__ u32 pk2(float a, float b){
    union { __hip_bfloat162 bf; u32 u; } cv;
    cv.bf = __float22bfloat162_rn(make_float2(a, b));   // low 16 bits = first k
    return cv.u;
}

template <typename T>
__device__ __forceinline__ auto mfma_sel(T a, T b, f32x16 c, int)
    -> decltype(__builtin_amdgcn_mfma_f32_32x32x16_bf16(a, b, c, 0, 0, 0)) {
    return __builtin_amdgcn_mfma_f32_32x32x16_bf16(a, b, c, 0, 0, 0);
}
template <typename T>
__device__ __forceinline__ f32x16 mfma_sel(T a, T b, f32x16 c, long) {
    return __builtin_amdgcn_mfma_f32_32x32x16_bf16(
        __builtin_bit_cast(bh8, a), __builtin_bit_cast(bh8, b), c, 0, 0, 0);
}
__device__ __forceinline__ f32x16 mfma_u4(uint4 a, uint4 b, f32x16 c){
    return mfma_sel(__builtin_bit_cast(short8, a), __builtin_bit_cast(short8, b), c, 0);
}

// packed ReLU (v_pk_max_f32 when available)
__device__ __forceinline__ f32x16 relu16(f32x16 a){
#if __has_builtin(__builtin_elementwise_max)
    return __builtin_elementwise_max(a, (f32x16)(0.f));
#else
#pragma unroll
    for (int i = 0; i < 16; ++i) a[i] = fmaxf(a[i], 0.f);
    return a;
#endif
}

// D-tile (col=lane&31, row=(reg&3)+8*(reg>>2)+4*(lane>>5)) -> next-layer B frags
__device__ __forceinline__ void dtile_to_b(f32x16 d, uint4& b0, uint4& b1){
    u32 p0 = pk2(d[0], d[1]),   p1 = pk2(d[2], d[3]);
    u32 p2 = pk2(d[4], d[5]),   p3 = pk2(d[6], d[7]);
    u32 p4 = pk2(d[8], d[9]),   p5 = pk2(d[10], d[11]);
    u32 p6 = pk2(d[12], d[13]), p7 = pk2(d[14], d[15]);
    auto r0 = __builtin_amdgcn_permlane32_swap(p0, p2, false, false);
    auto r1 = __builtin_amdgcn_permlane32_swap(p1, p3, false, false);
    auto r2 = __builtin_amdgcn_permlane32_swap(p4, p6, false, false);
    auto r3 = __builtin_amdgcn_permlane32_swap(p5, p7, false, false);
    b0 = make_uint4((u32)r0[0], (u32)r1[0], (u32)r0[1], (u32)r1[1]);
    b1 = make_uint4((u32)r2[0], (u32)r3[0], (u32)r2[1], (u32)r3[1]);
}

// ======================= prep: pack weights (+ bf16 table) =======================
__global__ __launch_bounds__(256) void prep(
    const float* __restrict__ v2e_w,
    const float* __restrict__ w_r1_w, const float* __restrict__ w_r1_b,
    const float* __restrict__ w_r2_w, const float* __restrict__ w_r2_b,
    const float* __restrict__ att1_w, const float* __restrict__ att1_b,
    const float* __restrict__ att2_w, const float* __restrict__ att2_b,
    const float* __restrict__ att3_w,
    u32* __restrict__ ws, int table_n, int woff)
{
    const int g = blockIdx.x * 256 + threadIdx.x;
    if (g < table_n) {
        const float4* src = (const float4*)v2e_w + (size_t)g * 2;
        float4 a = src[0], b = src[1];
        uint4 o; o.x = pk2(a.x, a.y); o.y = pk2(a.z, a.w);
                 o.z = pk2(b.x, b.y); o.w = pk2(b.z, b.w);
        ((uint4*)ws)[g] = o;
        return;
    }
    int q = g - table_n;
    u32* wbase = ws + woff;
    if (q < 2560) {
        const int c = q >> 6, l = q & 63, lo = l & 31, h = l >> 5;
        const float* W; int ldw, ft, kc, colb;
        if (c < 8)       { W = w_r1_w; ldw = 65;  ft = c >> 2;       kc = c & 3;       colb = 0; }
        else if (c < 16) { W = w_r2_w; ldw = 64;  ft = (c - 8) >> 2; kc = (c - 8) & 3; colb = 0; }
        else if (c < 32) { int c3 = c - 16; W = att1_w; ldw = 128; ft = c3 >> 3; kc = c3 & 3; colb = 64 * ((c3 >> 2) & 1); }
        else             { int c4 = c - 32; W = att2_w; ldw = 64;  ft = c4 >> 2; kc = c4 & 3; colb = 0; }
        const float* p = W + (32 * ft + lo) * ldw + colb + 16 * kc + 8 * h;
        uint4 o; o.x = pk2(p[0], p[1]); o.y = pk2(p[2], p[3]);
                 o.z = pk2(p[4], p[5]); o.w = pk2(p[6], p[7]);
        ((uint4*)wbase)[c * 64 + l] = o;
        return;
    }
    q -= 2560;
    if (q < 256) {
        const int layer = q >> 6, ft = (q >> 5) & 1, h = (q >> 4) & 1, rg = q & 15;
        const float* bp = layer == 0 ? w_r1_b : layer == 1 ? w_r2_b : layer == 2 ? att1_b : att2_b;
        ((float*)wbase)[BIAS_OFF + q] = bp[32 * ft + (rg & 3) + 8 * (rg >> 2) + 4 * h];
        return;
    }
    q -= 256;
    if (q < 64) {
        const int ft = (q >> 5) & 1, h = (q >> 4) & 1, rg = q & 15;
        ((float*)wbase)[WR_OFF + q] = w_r1_w[(32 * ft + (rg & 3) + 8 * (rg >> 2) + 4 * h) * 65 + 64];
        return;
    }
    q -= 64;
    if (q < 64) {
        const int ft = (q >> 5) & 1, h = (q >> 4) & 1, rg = q & 15;
        ((float*)wbase)[AT3_OFF + q] = att3_w[32 * ft + (rg & 3) + 8 * (rg >> 2) + 4 * h];
    }
}

// ======================= main: 4 waves x 2 tiles of 32 rows, 4 blocks/CU =======================
template<int USE_TAB>
__global__ __launch_bounds__(256, 4) void uv_agg(
    const int* __restrict__ nodes,
    const int* __restrict__ history_uv,
    const float* __restrict__ history_r,
    const float* __restrict__ u2e_w,
    const float* __restrict__ v2e_w,
    const float* __restrict__ att3_b,
    const u32* __restrict__ ws,
    float* __restrict__ out)
{
    const int b  = blockIdx.x;
    const int t  = threadIdx.x;
    const int w  = t >> 6;
    const int l  = t & 63;
    const int lo = l & 31;
    const int h  = l >> 5;

    constexpr int woff = USE_TAB ? TABW : 0;
    const uint4* WF = (const uint4*)(ws + woff);
    const float* F  = (const float*)(ws + woff);

    // word col c of row m stored at q = c ^ ((m&15)<<1)  (pair-preserving -> b64 ops)
    __shared__ u32   oh_lds[224 * 32];   // 28 KB (rows 200-223 hold clamped duplicates; att=0 masks them)
    __shared__ float red[4][64];
    __shared__ float ssum[4];
    __shared__ u32   u_lds[32];

    if (t < 32) {
        const float2 uv = ((const float2*)(u2e_w + (size_t)nodes[b] * 64))[t];
        u_lds[t] = pk2(uv.x, uv.y);
    }
    __syncthreads();   // u_lds ready; everything after is barrier-free until epilogue
                       // (oh_lds stash + layer-3/finale reads are wave-private)

    const bool full = (w != 3);          // wave 3's tile 2 (rows 224-255) is all pad

    const int hb  = b * Hn;
    const int m0  = 64 * w + lo;
    const int m1  = m0 + 32;
    const int mi0 = m0 < Hn ? m0 : Hn - 1;
    const int mi1 = m1 < Hn ? m1 : Hn - 1;
    const int vidx0 = history_uv[hb + mi0];
    float rv[2];
    rv[0] = history_r[hb + mi0];
    rv[1] = history_r[hb + mi1];

    // ---- e_uv B-fragments (tile 2 only for full waves)
    uint4 eB[2][4];
    if constexpr (USE_TAB) {
        const uint4* t0 = (const uint4*)ws + (size_t)vidx0 * 8;
#pragma unroll
        for (int kc = 0; kc < 4; ++kc) eB[0][kc] = t0[2*kc + h];
        if (full) {
            const uint4* t1 = (const uint4*)ws + (size_t)history_uv[hb + mi1] * 8;
#pragma unroll
            for (int kc = 0; kc < 4; ++kc) eB[1][kc] = t1[2*kc + h];
        }
    } else {
        const float4* p0 = (const float4*)(v2e_w + (size_t)vidx0 * 64);
#pragma unroll
        for (int kc = 0; kc < 4; ++kc){
            float4 a = p0[4*kc + 2*h], c = p0[4*kc + 2*h + 1];
            eB[0][kc] = make_uint4(pk2(a.x, a.y), pk2(a.z, a.w), pk2(c.x, c.y), pk2(c.z, c.w));
        }
        if (full) {
            const float4* p1 = (const float4*)(v2e_w + (size_t)history_uv[hb + mi1] * 64);
#pragma unroll
            for (int kc = 0; kc < 4; ++kc){
                float4 a = p1[4*kc + 2*h], c = p1[4*kc + 2*h + 1];
                eB[1][kc] = make_uint4(pk2(a.x, a.y), pk2(a.z, a.w), pk2(c.x, c.y), pk2(c.z, c.w));
            }
        }
    }

    // ---- layer 1: x1 = relu(W1[:,:64] @ e + w1r*r + b1)
    uint4 x1B[2][4];
#pragma unroll
    for (int ft = 0; ft < 2; ++ft){
        uint4 W[4];
#pragma unroll
        for (int kc = 0; kc < 4; ++kc) W[kc] = WF[(ft*4 + kc)*64 + l];
        const f32x16 bv = *(const f32x16*)(F + BIAS_OFF + ft*32 + h*16);
        const f32x16 wv = *(const f32x16*)(F + WR_OFF  + ft*32 + h*16);
#pragma unroll
        for (int rt = 0; rt < 2; ++rt){
            if (rt == 0 || full) {
                f32x16 a = wv * rv[rt] + bv;       // packed fma
                __builtin_amdgcn_s_setprio(1);
#pragma unroll
                for (int kc = 0; kc < 4; ++kc) a = mfma_u4(W[kc], eB[rt][kc], a);
                __builtin_amdgcn_s_setprio(0);
                a = relu16(a);
                dtile_to_b(a, x1B[rt][2*ft], x1B[rt][2*ft+1]);
            }
        }
    }

    // ---- layer 2: o_history = relu(W2 @ x1 + b2)  -> straight into LDS
#pragma unroll
    for (int ft = 0; ft < 2; ++ft){
        uint4 W[4];
#pragma unroll
        for (int kc = 0; kc < 4; ++kc) W[kc] = WF[(8 + ft*4 + kc)*64 + l];
        const f32x16 bv = *(const f32x16*)(F + BIAS_OFF + 64 + ft*32 + h*16);
#pragma unroll
        for (int rt = 0; rt < 2; ++rt){
            if (rt == 0 || full) {
                f32x16 a = bv;
                __builtin_amdgcn_s_setprio(1);
#pragma unroll
                for (int kc = 0; kc < 4; ++kc) a = mfma_u4(W[kc], x1B[rt][kc], a);
                __builtin_amdgcn_s_setprio(0);
                a = relu16(a);
                uint4 b0, b1;
                dtile_to_b(a, b0, b1);
                const int m = 64 * w + 32 * rt + lo;   // < 224 always (wave3 rt1 skipped)
                uint2* oh2 = (uint2*)oh_lds;
                const int x  = (lo & 15) << 1;
                const int q0 = (16*ft + 4*h) ^ x;      // c0 = 8*(2ft)+4h
                const int base = m * 16;
                oh2[base + ( q0      >> 1)] = make_uint2(b0.x, b0.y);
                oh2[base + ((q0 ^ 2) >> 1)] = make_uint2(b0.z, b0.w);
                oh2[base + ((q0 ^ 8) >> 1)] = make_uint2(b1.x, b1.y);
                oh2[base + ((q0 ^10) >> 1)] = make_uint2(b1.z, b1.w);
            }
        }
    }

    // ---- layer 3: a1 = relu(A1 @ [oh ; u] + b)  K=128; u-part computed once per ft
    uint4 a1B[2][4];
#pragma unroll
    for (int ft = 0; ft < 2; ++ft){
        f32x16 accu = *(const f32x16*)(F + BIAS_OFF + 128 + ft*32 + h*16);
        {
            uint4 Wu[4];
#pragma unroll
            for (int kc = 0; kc < 4; ++kc) Wu[kc] = WF[(16 + ft*8 + 4 + kc)*64 + l];
            __builtin_amdgcn_s_setprio(1);
#pragma unroll
            for (int kc = 0; kc < 4; ++kc){
                uint4 uu = *(const uint4*)&u_lds[8*kc + 4*h];
                accu = mfma_u4(Wu[kc], uu, accu);
            }
            __builtin_amdgcn_s_setprio(0);
        }
        uint4 Wo[4];
#pragma unroll
        for (int kc = 0; kc < 4; ++kc) Wo[kc] = WF[(16 + ft*8 + kc)*64 + l];
#pragma unroll
        for (int rt = 0; rt < 2; ++rt){
            if (rt == 0 || full) {
                const int m = 64 * w + 32 * rt + lo;
                const int x = (lo & 15) << 1;
                const uint2* oh2 = (const uint2*)oh_lds;
                uint4 frag[4];
#pragma unroll
                for (int kc = 0; kc < 4; ++kc){
                    const int q = (8*kc + 4*h) ^ x;
                    uint2 ra = oh2[m*16 + ( q      >> 1)];
                    uint2 rb = oh2[m*16 + ((q ^ 2) >> 1)];
                    frag[kc] = make_uint4(ra.x, ra.y, rb.x, rb.y);
                }
                f32x16 a = accu;
                __builtin_amdgcn_s_setprio(1);
#pragma unroll
                for (int kc = 0; kc < 4; ++kc) a = mfma_u4(Wo[kc], frag[kc], a);
                __builtin_amdgcn_s_setprio(0);
                a = relu16(a);
                dtile_to_b(a, a1B[rt][2*ft], a1B[rt][2*ft+1]);
            }
        }
    }

    // ---- layer 4 + logit dot
    float lgp[2] = {0.f, 0.f};
#pragma unroll
    for (int ft = 0; ft < 2; ++ft){
        uint4 W[4];
#pragma unroll
        for (int kc = 0; kc < 4; ++kc) W[kc] = WF[(32 + ft*4 + kc)*64 + l];
        const f32x16 bv = *(const f32x16*)(F + BIAS_OFF + 192 + ft*32 + h*16);
        const f32x16 a3 = *(const f32x16*)(F + AT3_OFF + ft*32 + h*16);
#pragma unroll
        for (int rt = 0; rt < 2; ++rt){
            if (rt == 0 || full) {
                f32x16 a = bv;
                __builtin_amdgcn_s_setprio(1);
#pragma unroll
                for (int kc = 0; kc < 4; ++kc) a = mfma_u4(W[kc], a1B[rt][kc], a);
                __builtin_amdgcn_s_setprio(0);
                f32x16 p = relu16(a) * a3;
                float d0 = (p[0] + p[1]) + (p[2] + p[3]);
                float d1 = (p[4] + p[5]) + (p[6] + p[7]);
                float d2 = (p[8] + p[9]) + (p[10] + p[11]);
                float d3 = (p[12] + p[13]) + (p[14] + p[15]);
                lgp[rt] += (d0 + d1) + (d2 + d3);
            }
        }
    }
    const float b3 = att3_b[0];
    float lg0 = lgp[0] + __shfl_xor(lgp[0], 32, 64) + b3;
    float lg1 = lgp[1] + __shfl_xor(lgp[1], 32, 64) + b3;
    if (m0 >= Hn) lg0 = -1e30f;
    if (m1 >= Hn || !full) lg1 = -1e30f;

    // ---- softmax over 200 rows (no max pass: logits bounded, shift-invariant ratio)
    const float e0 = exp2f(lg0 * 1.4426950408889634f);
    const float e1 = exp2f(lg1 * 1.4426950408889634f);
    float sm = e0 + e1;
#pragma unroll
    for (int d = 16; d >= 1; d >>= 1) sm += __shfl_xor(sm, d, 64);
    if (l == 0) ssum[w] = sm;
    __syncthreads();
    const float inv = 1.f / (ssum[0] + ssum[1] + ssum[2] + ssum[3]);
    // lane (lo,h) holds att numerator for row 64w+32h+lo (uniform across half-pairs)
    const float avv = (h ? e1 : e0) * inv;

    // ---- weighted sum over this wave's 64 rows (h-split; att via shfl, no LDS/barrier)
    float s0 = 0.f, s1 = 0.f;
#pragma unroll 8
    for (int i = 0; i < 32; ++i){
        const int row = 64 * w + 32 * h + i;
        const int ri  = row < 224 ? row : Hn - 1;     // only wave3/h1 tail clamps
        const u32 wv  = oh_lds[ri * 32 + (lo ^ ((ri & 15) << 1))];
        const float av = __shfl(avv, 32 * h + i, 64); // 0 for pad rows
        s0 = fmaf(__uint_as_float(wv << 16), av, s0);
        s1 = fmaf(__uint_as_float(wv & 0xffff0000u), av, s1);
    }
    s0 += __shfl_xor(s0, 32, 64);
    s1 += __shfl_xor(s1, 32, 64);
    if (l < 32){ red[w][2 * lo] = s0; red[w][2 * lo + 1] = s1; }
    __syncthreads();
    if (t < 64)
        out[b * 64 + t] = red[0][t] + red[1][t] + red[2][t] + red[3][t];
}

extern "C" void kernel_launch(void* const* d_in, const int* in_sizes, int n_in,
                              void* d_out, int out_size, void* d_ws, size_t ws_size,
                              hipStream_t stream) {
    u32* ws = (u32*)d_ws;
    const size_t need_tab = (size_t)(TABW + WTOT) * 4;
    const int use_tab = (ws_size >= need_tab) ? 1 : 0;
    const int woff    = use_tab ? TABW : 0;
    const int table_n = use_tab ? 800000 : 0;
    const int prep_threads = table_n + 2944;
    const int prep_blocks  = (prep_threads + 255) / 256;

    prep<<<prep_blocks, 256, 0, stream>>>(
        (const float*)d_in[4],
        (const float*)d_in[5],  (const float*)d_in[6],
        (const float*)d_in[7],  (const float*)d_in[8],
        (const float*)d_in[9],  (const float*)d_in[10],
        (const float*)d_in[11], (const float*)d_in[12],
        (const float*)d_in[13],
        ws, table_n, woff);

    if (use_tab) {
        uv_agg<1><<<Bn, 256, 0, stream>>>(
            (const int*)d_in[0], (const int*)d_in[1], (const float*)d_in[2],
            (const float*)d_in[3], (const float*)d_in[4], (const float*)d_in[14],
            ws, (float*)d_out);
    } else {
        uv_agg<0><<<Bn, 256, 0, stream>>>(
            (const int*)d_in[0], (const int*)d_in[1], (const float*)d_in[2],
            (const float*)d_in[3], (const float*)d_in[4], (const float*)d_in[14],
            ws, (float*)d_out);
    }
}